// Round 7
// baseline (74.731 us; speedup 1.0000x reference)
//
#include <hip/hip_runtime.h>
#include <math.h>

#define GD 128   // dynamic/feature dim
#define ELLW 64  // ELL width; max in-degree of restricted rows (avg ~10, Poisson tail << 64)
#define NSEG 512 // passA grid size == number of private 1-hop segments

// ---------------- pass A: 1-hop expansion into private per-block segments ----------------
// No pre-zeroed globals: codeid set lives in an LDS bitmap; hits are appended to
// list1[bid*MAXH..] with an LDS counter; bcnt[bid] is written unconditionally.
// Also zeroes cntarr inline (not touched by anything else in this kernel).
__global__ __launch_bounds__(256) void passA(const int* __restrict__ codeid, int B,
                                             const int* __restrict__ erow,
                                             const int* __restrict__ ecol, int E,
                                             int N, int MAXH,
                                             int* __restrict__ list1,
                                             int* __restrict__ bcnt,
                                             int* __restrict__ cntarr) {
    extern __shared__ unsigned int bm[];  // (N+31)/32 words
    __shared__ int lcnt;
    int t = threadIdx.x;
    int words = (N + 31) >> 5;
    for (int i = t; i < words; i += 256) bm[i] = 0;
    if (t == 0) lcnt = 0;
    __syncthreads();
    for (int i = t; i < B; i += 256) {
        int c = codeid[i];
        atomicOr(&bm[c >> 5], 1u << (c & 31));
    }
    __syncthreads();

    int gid = blockIdx.x * 256 + t, gs = gridDim.x * 256;
    // inline zero of cntarr (consumed by passB next; no race here)
    for (int i = gid; i < N; i += gs) cntarr[i] = 0;
    // E-scan: append 1-hop destination nodes of codeid-rooted edges
    int* seg = list1 + (size_t)blockIdx.x * MAXH;
    for (int e = gid; e < E; e += gs) {
        int r = erow[e];
        if ((bm[r >> 5] >> (r & 31)) & 1u) {
            int idx = atomicAdd(&lcnt, 1);  // LDS atomic, cheap
            seg[idx] = ecol[e];
        }
    }
    __syncthreads();
    if (t == 0) bcnt[blockIdx.x] = lcnt;
}

// ---------------- pass B: ELL build; membership via LDS bitmap (codeid U segments) ----------------
__global__ __launch_bounds__(256) void passB(const int* __restrict__ erow,
                                             const int* __restrict__ ecol,
                                             const float* __restrict__ ev, int E,
                                             const int* __restrict__ codeid, int B,
                                             const int* __restrict__ list1,
                                             const int* __restrict__ bcnt,
                                             int MAXH, int N,
                                             int* __restrict__ cnt,
                                             int* __restrict__ ellc,
                                             float* __restrict__ ellv) {
    extern __shared__ unsigned int bm[];  // (N+31)/32 words
    int t = threadIdx.x;
    int words = (N + 31) >> 5;
    for (int i = t; i < words; i += 256) bm[i] = 0;
    __syncthreads();
    for (int i = t; i < B; i += 256) {
        int c = codeid[i];
        atomicOr(&bm[c >> 5], 1u << (c & 31));
    }
    for (int s = t; s < NSEG; s += 256) {
        int c = bcnt[s];
        const int* seg = list1 + (size_t)s * MAXH;
        for (int k = 0; k < c; ++k) {
            int u = seg[k];
            atomicOr(&bm[u >> 5], 1u << (u & 31));
        }
    }
    __syncthreads();

    int gid = blockIdx.x * 256 + t, gs = gridDim.x * 256;
    for (int e = gid; e < E; e += gs) {
        int r = erow[e];
        if ((bm[r >> 5] >> (r & 31)) & 1u) {
            int idx = atomicAdd(&cnt[r], 1);  // distributed: ~10 per address
            if (idx < ELLW) {
                ellc[(size_t)r * ELLW + idx] = ecol[e];
                ellv[(size_t)r * ELLW + idx] = ev[e];
            }
        }
    }
}

// ---------------- layer 1: gather-then-GEMV + blend + relu over segmented U rows ----------------
// Duplicate rows across segments recompute identical values -> benign write races.
__device__ __forceinline__ void l1_row(int r, int sub, int j, float gx[2][GD],
                                       const float* __restrict__ X,
                                       const float* __restrict__ W1,
                                       const float* __restrict__ init,
                                       const int* __restrict__ cnt,
                                       const int* __restrict__ ellc,
                                       const float* __restrict__ ellv,
                                       float* __restrict__ x1) {
    if (r >= 0) {
        int c = cnt[r]; if (c > ELLW) c = ELLW;
        const int* ec = ellc + (size_t)r * ELLW;
        const float* evv = ellv + (size_t)r * ELLW;
        float g = 0.f;
        for (int k = 0; k < c; ++k)
            g += evv[k] * X[(size_t)ec[k] * GD + j];  // coalesced 512B row reads
        gx[sub][j] = g;
    }
    __syncthreads();
    if (r >= 0) {
        float a0 = 0.f, a1 = 0.f;
        const float* gp = gx[sub];
#pragma unroll 8
        for (int k = 0; k < GD; k += 2) {
            a0 += gp[k] * W1[(size_t)k * GD + j];
            a1 += gp[k + 1] * W1[(size_t)(k + 1) * GD + j];
        }
        x1[(size_t)r * GD + j] = fmaxf(0.1f * (a0 + a1) + 0.9f * init[(size_t)r * GD + j], 0.f);
    }
    __syncthreads();  // protect gx reuse
}

__global__ __launch_bounds__(256) void gath_gemm1(const float* __restrict__ X,
                                                  const float* __restrict__ W1,
                                                  const float* __restrict__ init,
                                                  const int* __restrict__ cnt,
                                                  const int* __restrict__ ellc,
                                                  const float* __restrict__ ellv,
                                                  const int* __restrict__ codeid, int B,
                                                  const int* __restrict__ list1,
                                                  const int* __restrict__ bcnt, int MAXH,
                                                  const float* __restrict__ patient,
                                                  const float* __restrict__ W_ih,
                                                  const float* __restrict__ b_ih,
                                                  const float* __restrict__ b_hh,
                                                  const int* __restrict__ patientid,
                                                  float* __restrict__ pc,
                                                  float* __restrict__ x1) {
    __shared__ float gx[2][GD];
    int t = threadIdx.x;
    int sub = t >> 7, j = t & 127;

    if (blockIdx.x == gridDim.x - 1 && t < GD) {
        // patient-GEMV hoist (same for all b): pc = b_ih + b_hh + patient[pid] @ W_ih[:, :128]^T
        int pid = patientid[0];
        const float* wih = W_ih + (size_t)t * 257;
        const float* pp = patient + (size_t)pid * GD;
        float a0 = 0.f, a1 = 0.f;
#pragma unroll 8
        for (int k = 0; k < GD; k += 2) {
            a0 += pp[k] * wih[k];
            a1 += pp[k + 1] * wih[k + 1];
        }
        pc[t] = b_ih[t] + b_hh[t] + a0 + a1;
    }

    if (blockIdx.x < NSEG) {
        // one private 1-hop segment per block
        int n = bcnt[blockIdx.x];
        const int* seg = list1 + (size_t)blockIdx.x * MAXH;
        for (int i0 = 0; i0 < n; i0 += 2) {
            int i = i0 + sub;
            int r = (i < n) ? seg[i] : -1;
            l1_row(r, sub, j, gx, X, W1, init, cnt, ellc, ellv, x1);
        }
    } else {
        // blocks >= NSEG share the codeid segment
        int nb2 = (gridDim.x - NSEG) * 2;
        int start = (blockIdx.x - NSEG) * 2;
        for (int i0 = start; i0 < B; i0 += nb2) {
            int i = i0 + sub;
            int r = (i < B) ? codeid[i] : -1;
            l1_row(r, sub, j, gx, X, W1, init, cnt, ellc, ellv, x1);
        }
    }
}

// ---------------- layer 2 gather + GEMV + RNNCell + L2 norm; 256 thr, 2-way k-split ----------------
__global__ __launch_bounds__(256) void gath2_rnn(const float* __restrict__ x1,
                                                 const float* __restrict__ init,
                                                 const float* __restrict__ timediffs,
                                                 const float* __restrict__ features,
                                                 const float* __restrict__ W2,
                                                 const float* __restrict__ W_ih,
                                                 const float* __restrict__ W_hh,
                                                 const int* __restrict__ codeid,
                                                 const int* __restrict__ cnt,
                                                 const int* __restrict__ ellc,
                                                 const float* __restrict__ ellv,
                                                 const float* __restrict__ pc,
                                                 float* __restrict__ out) {
    __shared__ float p2[2][GD];
    __shared__ float gx[GD];
    __shared__ float feat[GD];
    __shared__ float ce[GD];
    __shared__ float red[GD];
    int b = blockIdx.x;
    int t = threadIdx.x, j = t & 127, half = t >> 7;
    int cid = codeid[b];

    if (half == 0) feat[j] = features[(size_t)b * GD + j];

    // gather partial (k split across halves)
    int c = cnt[cid]; if (c > ELLW) c = ELLW;
    const int* ec = ellc + (size_t)cid * ELLW;
    const float* evv = ellv + (size_t)cid * ELLW;
    int kmid = (c + 1) >> 1;
    int k0 = half ? kmid : 0;
    int k1 = half ? c : kmid;
    float g = 0.f;
    for (int k = k0; k < k1; ++k) g += evv[k] * x1[(size_t)ec[k] * GD + j];
    p2[half][j] = g;
    __syncthreads();
    if (half == 0) gx[j] = p2[0][j] + p2[1][j];
    __syncthreads();

    // W2 GEMV partial: half h covers k in [64h, 64h+64)
    {
        int kb = half << 6;
        float a0 = 0.f, a1 = 0.f;
#pragma unroll 8
        for (int k = 0; k < 64; k += 2) {
            a0 += gx[kb + k] * W2[(size_t)(kb + k) * GD + j];
            a1 += gx[kb + k + 1] * W2[(size_t)(kb + k + 1) * GD + j];
        }
        p2[half][j] = a0 + a1;
    }
    __syncthreads();
    if (half == 0)
        ce[j] = fmaxf(0.1f * (p2[0][j] + p2[1][j]) + 0.9f * init[(size_t)cid * GD + j], 0.f);
    __syncthreads();

    // RNN GEMV partials (features-part + hh-part); patient part precomputed in pc[]
    {
        const float* wih = W_ih + (size_t)j * 257;
        const float* whh = W_hh + (size_t)j * GD;
        int kb = half << 6;
        float a0 = (half == 0) ? (pc[j] + timediffs[b] * wih[GD]) : 0.f;
        float a1 = 0.f;
#pragma unroll 8
        for (int k = 0; k < 64; k += 2) {
            a0 += feat[kb + k] * wih[129 + kb + k];
            a1 += feat[kb + k + 1] * wih[129 + kb + k + 1];
        }
#pragma unroll 8
        for (int k = 0; k < 64; k += 2) {
            a0 += ce[kb + k] * whh[kb + k];
            a1 += ce[kb + k + 1] * whh[kb + k + 1];
        }
        p2[half][j] = a0 + a1;
    }
    __syncthreads();

    float h = 0.f;
    if (half == 0) {
        h = tanhf(p2[0][j] + p2[1][j]);
        red[j] = h * h;
    }
    __syncthreads();
    for (int s = 64; s > 0; s >>= 1) {
        if (half == 0 && j < s) red[j] += red[j + s];
        __syncthreads();
    }
    if (half == 0) {
        float nrm = fmaxf(sqrtf(red[0]), 1e-12f);
        out[(size_t)b * GD + j] = h / nrm;
    }
}

// ================= launcher (4 launches, no pre-zeroed globals) =================

extern "C" void kernel_launch(void* const* d_in, const int* in_sizes, int n_in,
                              void* d_out, int out_size, void* d_ws, size_t ws_size,
                              hipStream_t stream) {
    const float* code_dynamic = (const float*)d_in[0];
    const float* init_cd      = (const float*)d_in[1];
    const float* patient      = (const float*)d_in[2];
    const float* timediffs    = (const float*)d_in[3];
    const float* features     = (const float*)d_in[4];
    const float* edge_val     = (const float*)d_in[5];
    const float* W1           = (const float*)d_in[6];
    const float* W2           = (const float*)d_in[7];
    const float* W_ih         = (const float*)d_in[8];
    const float* b_ih         = (const float*)d_in[9];
    const float* W_hh         = (const float*)d_in[10];
    const float* b_hh         = (const float*)d_in[11];
    const int* edge_row       = (const int*)d_in[12];
    const int* edge_col       = (const int*)d_in[13];
    const int* codeid         = (const int*)d_in[14];
    const int* patientid      = (const int*)d_in[15];

    int N = in_sizes[0] / GD;   // 60000
    int E = in_sizes[5];        // 600000
    int B = in_sizes[14];       // 256
    size_t nd = (size_t)N * GD;

    // private-segment capacity: max edges one passA block can visit (rounded to 256)
    int MAXH = 256 * ((E + NSEG * 256 - 1) / (NSEG * 256));

    // workspace layout (all 16B-aligned)
    float* x1buf  = (float*)d_ws;                        // N*GD f32
    int*   ellc   = (int*)(x1buf + nd);                  // N*ELLW
    float* ellv   = (float*)(ellc + (size_t)N * ELLW);   // N*ELLW
    int*   cntarr = (int*)(ellv + (size_t)N * ELLW);     // N (zeroed inside passA)
    int*   list1  = cntarr + N;                          // NSEG*MAXH
    int*   bcnt   = list1 + (size_t)NSEG * MAXH;         // NSEG
    float* pcbuf  = (float*)(bcnt + NSEG);               // GD

    size_t bmBytes = (size_t)((N + 31) / 32) * sizeof(unsigned int);  // 7.5 KB @ N=60000

    passA<<<NSEG, 256, bmBytes, stream>>>(codeid, B, edge_row, edge_col, E,
                                          N, MAXH, list1, bcnt, cntarr);
    passB<<<NSEG, 256, bmBytes, stream>>>(edge_row, edge_col, edge_val, E,
                                          codeid, B, list1, bcnt, MAXH, N,
                                          cntarr, ellc, ellv);
    gath_gemm1<<<1024, 256, 0, stream>>>(code_dynamic, W1, init_cd,
                                         cntarr, ellc, ellv,
                                         codeid, B, list1, bcnt, MAXH,
                                         patient, W_ih, b_ih, b_hh, patientid,
                                         pcbuf, x1buf);
    gath2_rnn<<<B, 256, 0, stream>>>(x1buf, init_cd, timediffs, features,
                                     W2, W_ih, W_hh, codeid,
                                     cntarr, ellc, ellv, pcbuf, (float*)d_out);
}

// Round 8
// 52.938 us; speedup vs baseline: 1.4117x; 1.4117x over previous
//
#include <hip/hip_runtime.h>
#include <math.h>

#define GD 128   // dynamic/feature dim
#define ELLW 64  // ELL width; max in-degree of restricted rows (avg ~10, Poisson tail << 64)
#define NSEG 512 // passA grid size == number of private 1-hop segments
#define NCOMP 16 // blocks of passB that also compact the bitmap into rowsU

// ---------------- pass A: 1-hop expansion into private per-block segments ----------------
// codeid set in LDS bitmap; hits appended to private segment; bcnt written unconditionally.
// Also zeroes cntarr + cnts inline (nothing else touches them in this kernel).
__global__ __launch_bounds__(256) void passA(const int* __restrict__ codeid, int B,
                                             const int* __restrict__ erow,
                                             const int* __restrict__ ecol, int E,
                                             int N, int MAXH,
                                             int* __restrict__ list1,
                                             int* __restrict__ bcnt,
                                             int* __restrict__ cntarr,
                                             int* __restrict__ cnts) {
    extern __shared__ unsigned int bm[];  // (N+31)/32 words
    __shared__ int lcnt;
    int t = threadIdx.x;
    int words = (N + 31) >> 5;
    for (int i = t; i < words; i += 256) bm[i] = 0;
    if (t == 0) lcnt = 0;
    __syncthreads();
    for (int i = t; i < B; i += 256) {
        int c = codeid[i];
        atomicOr(&bm[c >> 5], 1u << (c & 31));
    }
    __syncthreads();

    if (blockIdx.x == 0 && t < 8) cnts[t] = 0;
    int gid = blockIdx.x * 256 + t, gs = gridDim.x * 256;
    for (int i = gid; i < N; i += gs) cntarr[i] = 0;
    // E-scan: append 1-hop destinations of codeid-rooted edges to private segment
    int* seg = list1 + (size_t)blockIdx.x * MAXH;
    for (int e = gid; e < E; e += gs) {
        int r = erow[e];
        if ((bm[r >> 5] >> (r & 31)) & 1u) {
            int idx = atomicAdd(&lcnt, 1);  // LDS atomic
            seg[idx] = ecol[e];
        }
    }
    __syncthreads();
    if (t == 0) bcnt[blockIdx.x] = lcnt;
}

// ---------------- pass B: U-bitmap -> {ELL build (all blocks), rowsU compaction (16 blocks)} ----
__global__ __launch_bounds__(256) void passB(const int* __restrict__ erow,
                                             const int* __restrict__ ecol,
                                             const float* __restrict__ ev, int E,
                                             const int* __restrict__ codeid, int B,
                                             const int* __restrict__ list1,
                                             const int* __restrict__ bcnt,
                                             int MAXH, int N,
                                             int* __restrict__ cnt,
                                             int* __restrict__ ellc,
                                             float* __restrict__ ellv,
                                             int* __restrict__ rowsU,
                                             int* __restrict__ cntU) {
    extern __shared__ unsigned int bm[];  // (N+31)/32 words
    __shared__ int woff[4];
    __shared__ int cbase;
    int t = threadIdx.x;
    int words = (N + 31) >> 5;
    for (int i = t; i < words; i += 256) bm[i] = 0;
    __syncthreads();
    for (int i = t; i < B; i += 256) {
        int c = codeid[i];
        atomicOr(&bm[c >> 5], 1u << (c & 31));
    }
    for (int s = t; s < NSEG; s += 256) {
        int c = bcnt[s];
        const int* seg = list1 + (size_t)s * MAXH;
        for (int k = 0; k < c; ++k) {
            int u = seg[k];
            atomicOr(&bm[u >> 5], 1u << (u & 31));
        }
    }
    __syncthreads();

    // blocks 0..NCOMP-1: compact bitmap -> rowsU (duplicate-free, per-tile leader atomic)
    if (blockIdx.x < NCOMP) {
        int wid = t >> 6, lane = t & 63;
        int ntiles = (N + 255) >> 8;
        for (int tile = blockIdx.x; tile < ntiles; tile += NCOMP) {
            int i = (tile << 8) + t;
            int m = (i < N) ? ((bm[i >> 5] >> (i & 31)) & 1u) : 0;
            unsigned long long ball = __ballot(m != 0);
            if (lane == 0) woff[wid] = __popcll(ball);
            __syncthreads();
            if (t == 0) {
                int c0 = woff[0], c1 = woff[1], c2 = woff[2], c3 = woff[3];
                int tot = c0 + c1 + c2 + c3;
                cbase = tot ? atomicAdd(cntU, tot) : 0;
                woff[0] = 0; woff[1] = c0; woff[2] = c0 + c1; woff[3] = c0 + c1 + c2;
            }
            __syncthreads();
            if (m) rowsU[cbase + woff[wid] + __popcll(ball & ((1ULL << lane) - 1ULL))] = i;
            __syncthreads();
        }
    }

    // all blocks: restricted ELL build
    int gid = blockIdx.x * 256 + t, gs = gridDim.x * 256;
    for (int e = gid; e < E; e += gs) {
        int r = erow[e];
        if ((bm[r >> 5] >> (r & 31)) & 1u) {
            int idx = atomicAdd(&cnt[r], 1);  // distributed: ~10 per address
            if (idx < ELLW) {
                ellc[(size_t)r * ELLW + idx] = ecol[e];
                ellv[(size_t)r * ELLW + idx] = ev[e];
            }
        }
    }
}

// ---------------- layer 1: gather-then-GEMV + blend + relu over rowsU (even grid-stride) ----
// Gather is LDS-staged (ec/evv) and 4-way unrolled -> 4 independent X-row loads in flight.
__global__ __launch_bounds__(256) void gath_gemm1(const float* __restrict__ X,
                                                  const float* __restrict__ W1,
                                                  const float* __restrict__ init,
                                                  const int* __restrict__ cnt,
                                                  const int* __restrict__ ellc,
                                                  const float* __restrict__ ellv,
                                                  const int* __restrict__ rowsU,
                                                  const int* __restrict__ cntUp,
                                                  const float* __restrict__ patient,
                                                  const float* __restrict__ W_ih,
                                                  const float* __restrict__ b_ih,
                                                  const float* __restrict__ b_hh,
                                                  const int* __restrict__ patientid,
                                                  float* __restrict__ pc,
                                                  float* __restrict__ x1) {
    __shared__ float gx[2][GD];
    __shared__ int sec[2][ELLW];
    __shared__ float sev[2][ELLW];
    int t = threadIdx.x;
    int sub = t >> 7, j = t & 127;

    if (blockIdx.x == gridDim.x - 1 && t < GD) {
        // patient-GEMV hoist (same for all b): pc = b_ih + b_hh + patient[pid] @ W_ih[:, :128]^T
        int pid = patientid[0];
        const float* wih = W_ih + (size_t)t * 257;
        const float* pp = patient + (size_t)pid * GD;
        float a0 = 0.f, a1 = 0.f;
#pragma unroll 8
        for (int k = 0; k < GD; k += 2) {
            a0 += pp[k] * wih[k];
            a1 += pp[k + 1] * wih[k + 1];
        }
        pc[t] = b_ih[t] + b_hh[t] + a0 + a1;
    }

    int n = *cntUp;
    for (int base = blockIdx.x * 2; base < n; base += gridDim.x * 2) {
        int i = base + sub;
        int r = (i < n) ? rowsU[i] : -1;
        int c = 0;
        if (r >= 0) {
            c = cnt[r]; if (c > ELLW) c = ELLW;
            // parallel stage of ELL row into LDS
            if (j < c) {
                sec[sub][j] = ellc[(size_t)r * ELLW + j];
                sev[sub][j] = ellv[(size_t)r * ELLW + j];
            }
        }
        __syncthreads();
        if (r >= 0) {
            // 4-accumulator gather: 4 independent coalesced X-row loads in flight
            float g0 = 0.f, g1 = 0.f, g2 = 0.f, g3 = 0.f;
            int k = 0;
            for (; k + 3 < c; k += 4) {
                g0 += sev[sub][k]     * X[(size_t)sec[sub][k]     * GD + j];
                g1 += sev[sub][k + 1] * X[(size_t)sec[sub][k + 1] * GD + j];
                g2 += sev[sub][k + 2] * X[(size_t)sec[sub][k + 2] * GD + j];
                g3 += sev[sub][k + 3] * X[(size_t)sec[sub][k + 3] * GD + j];
            }
            for (; k < c; ++k) g0 += sev[sub][k] * X[(size_t)sec[sub][k] * GD + j];
            gx[sub][j] = (g0 + g1) + (g2 + g3);
        }
        __syncthreads();
        if (r >= 0) {
            float a0 = 0.f, a1 = 0.f, a2 = 0.f, a3 = 0.f;
            const float* gp = gx[sub];
#pragma unroll 8
            for (int k = 0; k < GD; k += 4) {
                a0 += gp[k]     * W1[(size_t)k       * GD + j];
                a1 += gp[k + 1] * W1[(size_t)(k + 1) * GD + j];
                a2 += gp[k + 2] * W1[(size_t)(k + 2) * GD + j];
                a3 += gp[k + 3] * W1[(size_t)(k + 3) * GD + j];
            }
            float acc = (a0 + a1) + (a2 + a3);
            x1[(size_t)r * GD + j] = fmaxf(0.1f * acc + 0.9f * init[(size_t)r * GD + j], 0.f);
        }
        __syncthreads();  // protect LDS reuse
    }
}

// ---------------- layer 2 gather + GEMV + RNNCell + L2 norm; 256 thr, 2-way k-split ----------------
__global__ __launch_bounds__(256) void gath2_rnn(const float* __restrict__ x1,
                                                 const float* __restrict__ init,
                                                 const float* __restrict__ timediffs,
                                                 const float* __restrict__ features,
                                                 const float* __restrict__ W2,
                                                 const float* __restrict__ W_ih,
                                                 const float* __restrict__ W_hh,
                                                 const int* __restrict__ codeid,
                                                 const int* __restrict__ cnt,
                                                 const int* __restrict__ ellc,
                                                 const float* __restrict__ ellv,
                                                 const float* __restrict__ pc,
                                                 float* __restrict__ out) {
    __shared__ float p2[2][GD];
    __shared__ float gx[GD];
    __shared__ float feat[GD];
    __shared__ float ce[GD];
    __shared__ float red[GD];
    __shared__ int sec[ELLW];
    __shared__ float sev[ELLW];
    int b = blockIdx.x;
    int t = threadIdx.x, j = t & 127, half = t >> 7;
    int cid = codeid[b];

    int c = cnt[cid]; if (c > ELLW) c = ELLW;
    if (t < c) {  // parallel ELL-row stage
        sec[t] = ellc[(size_t)cid * ELLW + t];
        sev[t] = ellv[(size_t)cid * ELLW + t];
    }
    if (half == 0) feat[j] = features[(size_t)b * GD + j];
    __syncthreads();

    // gather partial (k split across halves, 2 accumulators each)
    int kmid = (c + 1) >> 1;
    int k0 = half ? kmid : 0;
    int k1 = half ? c : kmid;
    {
        float g0 = 0.f, g1 = 0.f;
        int k = k0;
        for (; k + 1 < k1; k += 2) {
            g0 += sev[k]     * x1[(size_t)sec[k]     * GD + j];
            g1 += sev[k + 1] * x1[(size_t)sec[k + 1] * GD + j];
        }
        if (k < k1) g0 += sev[k] * x1[(size_t)sec[k] * GD + j];
        p2[half][j] = g0 + g1;
    }
    __syncthreads();
    if (half == 0) gx[j] = p2[0][j] + p2[1][j];
    __syncthreads();

    // W2 GEMV partial: half h covers k in [64h, 64h+64)
    {
        int kb = half << 6;
        float a0 = 0.f, a1 = 0.f, a2 = 0.f, a3 = 0.f;
#pragma unroll 8
        for (int k = 0; k < 64; k += 4) {
            a0 += gx[kb + k]     * W2[(size_t)(kb + k)     * GD + j];
            a1 += gx[kb + k + 1] * W2[(size_t)(kb + k + 1) * GD + j];
            a2 += gx[kb + k + 2] * W2[(size_t)(kb + k + 2) * GD + j];
            a3 += gx[kb + k + 3] * W2[(size_t)(kb + k + 3) * GD + j];
        }
        p2[half][j] = (a0 + a1) + (a2 + a3);
    }
    __syncthreads();
    if (half == 0)
        ce[j] = fmaxf(0.1f * (p2[0][j] + p2[1][j]) + 0.9f * init[(size_t)cid * GD + j], 0.f);
    __syncthreads();

    // RNN GEMV partials (features-part + hh-part); patient part precomputed in pc[]
    {
        const float* wih = W_ih + (size_t)j * 257;
        const float* whh = W_hh + (size_t)j * GD;
        int kb = half << 6;
        float a0 = (half == 0) ? (pc[j] + timediffs[b] * wih[GD]) : 0.f;
        float a1 = 0.f;
#pragma unroll 8
        for (int k = 0; k < 64; k += 2) {
            a0 += feat[kb + k] * wih[129 + kb + k];
            a1 += feat[kb + k + 1] * wih[129 + kb + k + 1];
        }
#pragma unroll 8
        for (int k = 0; k < 64; k += 2) {
            a0 += ce[kb + k] * whh[kb + k];
            a1 += ce[kb + k + 1] * whh[kb + k + 1];
        }
        p2[half][j] = a0 + a1;
    }
    __syncthreads();

    float h = 0.f;
    if (half == 0) {
        h = tanhf(p2[0][j] + p2[1][j]);
        red[j] = h * h;
    }
    __syncthreads();
    for (int s = 64; s > 0; s >>= 1) {
        if (half == 0 && j < s) red[j] += red[j + s];
        __syncthreads();
    }
    if (half == 0) {
        float nrm = fmaxf(sqrtf(red[0]), 1e-12f);
        out[(size_t)b * GD + j] = h / nrm;
    }
}

// ================= launcher (4 launches, no pre-zeroed globals) =================

extern "C" void kernel_launch(void* const* d_in, const int* in_sizes, int n_in,
                              void* d_out, int out_size, void* d_ws, size_t ws_size,
                              hipStream_t stream) {
    const float* code_dynamic = (const float*)d_in[0];
    const float* init_cd      = (const float*)d_in[1];
    const float* patient      = (const float*)d_in[2];
    const float* timediffs    = (const float*)d_in[3];
    const float* features     = (const float*)d_in[4];
    const float* edge_val     = (const float*)d_in[5];
    const float* W1           = (const float*)d_in[6];
    const float* W2           = (const float*)d_in[7];
    const float* W_ih         = (const float*)d_in[8];
    const float* b_ih         = (const float*)d_in[9];
    const float* W_hh         = (const float*)d_in[10];
    const float* b_hh         = (const float*)d_in[11];
    const int* edge_row       = (const int*)d_in[12];
    const int* edge_col       = (const int*)d_in[13];
    const int* codeid         = (const int*)d_in[14];
    const int* patientid      = (const int*)d_in[15];

    int N = in_sizes[0] / GD;   // 60000
    int E = in_sizes[5];        // 600000
    int B = in_sizes[14];       // 256
    size_t nd = (size_t)N * GD;

    // private-segment capacity: max edges one passA block can visit (rounded to 256)
    int MAXH = 256 * ((E + NSEG * 256 - 1) / (NSEG * 256));

    // workspace layout (all 16B-aligned)
    float* x1buf  = (float*)d_ws;                        // N*GD f32
    int*   ellc   = (int*)(x1buf + nd);                  // N*ELLW
    float* ellv   = (float*)(ellc + (size_t)N * ELLW);   // N*ELLW
    int*   cntarr = (int*)(ellv + (size_t)N * ELLW);     // N (zeroed inside passA)
    int*   list1  = cntarr + N;                          // NSEG*MAXH
    int*   bcnt   = list1 + (size_t)NSEG * MAXH;         // NSEG
    int*   cnts   = bcnt + NSEG;                         // 8 ints: [cntU] (zeroed in passA)
    int*   rowsU  = cnts + 8;                            // N
    float* pcbuf  = (float*)(rowsU + N);                 // GD

    size_t bmBytes = (size_t)((N + 31) / 32) * sizeof(unsigned int);  // 7.5 KB @ N=60000

    passA<<<NSEG, 256, bmBytes, stream>>>(codeid, B, edge_row, edge_col, E,
                                          N, MAXH, list1, bcnt, cntarr, cnts);
    passB<<<NSEG, 256, bmBytes, stream>>>(edge_row, edge_col, edge_val, E,
                                          codeid, B, list1, bcnt, MAXH, N,
                                          cntarr, ellc, ellv, rowsU, &cnts[0]);
    gath_gemm1<<<2048, 256, 0, stream>>>(code_dynamic, W1, init_cd,
                                         cntarr, ellc, ellv, rowsU, &cnts[0],
                                         patient, W_ih, b_ih, b_hh, patientid,
                                         pcbuf, x1buf);
    gath2_rnn<<<B, 256, 0, stream>>>(x1buf, init_cd, timediffs, features,
                                     W2, W_ih, W_hh, codeid,
                                     cntarr, ellc, ellv, pcbuf, (float*)d_out);
}

// Round 9
// 50.282 us; speedup vs baseline: 1.4862x; 1.0528x over previous
//
#include <hip/hip_runtime.h>
#include <math.h>

#define GD 128   // dynamic/feature dim
#define ELLW 64  // ELL width; max in-degree of restricted rows (avg ~10, Poisson tail << 64)
#define NSEG 512 // passA/passB grid size == number of private 1-hop segments

// ---------------- pass A: 1-hop expansion into private per-block segments ----------------
// codeid set in LDS bitmap; hits appended to private segment; bcnt written unconditionally.
// Also zeroes cntarr inline and computes the hoisted patient GEMV (last block).
__global__ __launch_bounds__(256) void passA(const int* __restrict__ codeid, int B,
                                             const int* __restrict__ erow,
                                             const int* __restrict__ ecol, int E,
                                             int N, int MAXH,
                                             int* __restrict__ list1,
                                             int* __restrict__ bcnt,
                                             int* __restrict__ cntarr,
                                             const float* __restrict__ patient,
                                             const float* __restrict__ W_ih,
                                             const float* __restrict__ b_ih,
                                             const float* __restrict__ b_hh,
                                             const int* __restrict__ patientid,
                                             float* __restrict__ pc) {
    extern __shared__ unsigned int bm[];  // (N+31)/32 words
    __shared__ int lcnt;
    int t = threadIdx.x;
    int words = (N + 31) >> 5;
    for (int i = t; i < words; i += 256) bm[i] = 0;
    if (t == 0) lcnt = 0;
    __syncthreads();
    for (int i = t; i < B; i += 256) {
        int c = codeid[i];
        atomicOr(&bm[c >> 5], 1u << (c & 31));
    }
    __syncthreads();

    if (blockIdx.x == gridDim.x - 1 && t < GD) {
        // pc = b_ih + b_hh + patient[pid] @ W_ih[:, :128]^T (identical for all b)
        int pid = patientid[0];
        const float* wih = W_ih + (size_t)t * 257;
        const float* pp = patient + (size_t)pid * GD;
        float a0 = 0.f, a1 = 0.f;
#pragma unroll 8
        for (int k = 0; k < GD; k += 2) {
            a0 += pp[k] * wih[k];
            a1 += pp[k + 1] * wih[k + 1];
        }
        pc[t] = b_ih[t] + b_hh[t] + a0 + a1;
    }

    int gid = blockIdx.x * 256 + t, gs = gridDim.x * 256;
    for (int i = gid; i < N; i += gs) cntarr[i] = 0;
    // E-scan: append 1-hop destinations of codeid-rooted edges to private segment
    int* seg = list1 + (size_t)blockIdx.x * MAXH;
    for (int e = gid; e < E; e += gs) {
        int r = erow[e];
        if ((bm[r >> 5] >> (r & 31)) & 1u) {
            int idx = atomicAdd(&lcnt, 1);  // LDS atomic
            seg[idx] = ecol[e];
        }
    }
    __syncthreads();
    if (t == 0) bcnt[blockIdx.x] = lcnt;
}

// ---------------- pass B: U-bitmap (codeid U segments) -> restricted ELL build ----------------
__global__ __launch_bounds__(256) void passB(const int* __restrict__ erow,
                                             const int* __restrict__ ecol,
                                             const float* __restrict__ ev, int E,
                                             const int* __restrict__ codeid, int B,
                                             const int* __restrict__ list1,
                                             const int* __restrict__ bcnt,
                                             int MAXH, int N,
                                             int* __restrict__ cnt,
                                             int* __restrict__ ellc,
                                             float* __restrict__ ellv) {
    extern __shared__ unsigned int bm[];  // (N+31)/32 words
    int t = threadIdx.x;
    int words = (N + 31) >> 5;
    for (int i = t; i < words; i += 256) bm[i] = 0;
    __syncthreads();
    for (int i = t; i < B; i += 256) {
        int c = codeid[i];
        atomicOr(&bm[c >> 5], 1u << (c & 31));
    }
    for (int s = t; s < NSEG; s += 256) {
        int c = bcnt[s];
        const int* seg = list1 + (size_t)s * MAXH;
        for (int k = 0; k < c; ++k) {
            int u = seg[k];
            atomicOr(&bm[u >> 5], 1u << (u & 31));
        }
    }
    __syncthreads();

    int gid = blockIdx.x * 256 + t, gs = gridDim.x * 256;
    for (int e = gid; e < E; e += gs) {
        int r = erow[e];
        if ((bm[r >> 5] >> (r & 31)) & 1u) {
            int idx = atomicAdd(&cnt[r], 1);  // distributed: ~10 per address
            if (idx < ELLW) {
                ellc[(size_t)r * ELLW + idx] = ecol[e];
                ellv[(size_t)r * ELLW + idx] = ev[e];
            }
        }
    }
}

// ---------------- fused: layer1 (per-neighbor, x1 LDS-only) + layer2 + RNNCell + L2 norm ----
// One block (512 thr = 4 subs x 128) per b. Duplicate x1 work across b's sharing neighbors
// is ~10% (neighbor sets nearly disjoint) -- cheaper than a kernel boundary + HBM roundtrip.
__global__ __launch_bounds__(512) void fused12(const float* __restrict__ X,
                                               const float* __restrict__ W1,
                                               const float* __restrict__ W2,
                                               const float* __restrict__ init,
                                               const int* __restrict__ cnt,
                                               const int* __restrict__ ellc,
                                               const float* __restrict__ ellv,
                                               const int* __restrict__ codeid,
                                               const float* __restrict__ timediffs,
                                               const float* __restrict__ features,
                                               const float* __restrict__ W_ih,
                                               const float* __restrict__ W_hh,
                                               const float* __restrict__ pc,
                                               float* __restrict__ out) {
    __shared__ int   sec[ELLW];
    __shared__ float sev[ELLW];
    __shared__ int   ncnt[ELLW];
    __shared__ int   nec[ELLW][ELLW];   // 16 KB
    __shared__ float nev[ELLW][ELLW];   // 16 KB
    __shared__ float gxs[4][GD];
    __shared__ float p2[4][GD];
    __shared__ float gx2[GD];
    __shared__ float feat[GD];
    __shared__ float ce[GD];
    __shared__ float red[GD];

    int b = blockIdx.x, t = threadIdx.x;
    int sub = t >> 7, j = t & 127;
    int cid = codeid[b];
    int c = cnt[cid]; if (c > ELLW) c = ELLW;

    if (t < c) { sec[t] = ellc[(size_t)cid * ELLW + t]; sev[t] = ellv[(size_t)cid * ELLW + t]; }
    if (t < GD) feat[t] = features[(size_t)b * GD + t];
    __syncthreads();
    if (t < c) { int cc = cnt[sec[t]]; ncnt[t] = cc > ELLW ? ELLW : cc; }
    __syncthreads();
    // stage all neighbor ELL rows in parallel
    for (int idx = t; idx < c * ELLW; idx += 512) {
        int i = idx >> 6, k = idx & 63;
        if (k < ncnt[i]) {
            nec[i][k] = ellc[(size_t)sec[i] * ELLW + k];
            nev[i][k] = ellv[(size_t)sec[i] * ELLW + k];
        }
    }
    __syncthreads();

    // layer 1 per neighbor (4 neighbors in flight, one per sub); accumulate gx2 partial
    float a2 = 0.f;
    int nrounds = (c + 3) >> 2;
    for (int ro = 0; ro < nrounds; ++ro) {
        int i = ro * 4 + sub;
        bool act = (i < c);
        if (act) {
            int cc = ncnt[i];
            float g0 = 0.f, g1 = 0.f, g2 = 0.f, g3 = 0.f;
            int k = 0;
            for (; k + 3 < cc; k += 4) {
                g0 += nev[i][k]     * X[(size_t)nec[i][k]     * GD + j];
                g1 += nev[i][k + 1] * X[(size_t)nec[i][k + 1] * GD + j];
                g2 += nev[i][k + 2] * X[(size_t)nec[i][k + 2] * GD + j];
                g3 += nev[i][k + 3] * X[(size_t)nec[i][k + 3] * GD + j];
            }
            for (; k < cc; ++k) g0 += nev[i][k] * X[(size_t)nec[i][k] * GD + j];
            gxs[sub][j] = (g0 + g1) + (g2 + g3);
        }
        __syncthreads();
        if (act) {
            float a0 = 0.f, a1 = 0.f, b2 = 0.f, b3 = 0.f;
            const float* gp = gxs[sub];
#pragma unroll 8
            for (int k = 0; k < GD; k += 4) {
                a0 += gp[k]     * W1[(size_t)k       * GD + j];
                a1 += gp[k + 1] * W1[(size_t)(k + 1) * GD + j];
                b2 += gp[k + 2] * W1[(size_t)(k + 2) * GD + j];
                b3 += gp[k + 3] * W1[(size_t)(k + 3) * GD + j];
            }
            float x1v = fmaxf(0.1f * ((a0 + a1) + (b2 + b3))
                              + 0.9f * init[(size_t)sec[i] * GD + j], 0.f);
            a2 += sev[i] * x1v;   // layer-2 gather, in-register
        }
        __syncthreads();  // protect gxs reuse
    }
    p2[sub][j] = a2;
    __syncthreads();
    if (t < GD) gx2[t] = (p2[0][t] + p2[1][t]) + (p2[2][t] + p2[3][t]);
    __syncthreads();

    // W2 GEMV: sub covers k in [32*sub, 32*sub+32)
    {
        int kb = sub << 5;
        float a0 = 0.f, a1 = 0.f, b2 = 0.f, b3 = 0.f;
#pragma unroll 8
        for (int k = 0; k < 32; k += 4) {
            a0 += gx2[kb + k]     * W2[(size_t)(kb + k)     * GD + j];
            a1 += gx2[kb + k + 1] * W2[(size_t)(kb + k + 1) * GD + j];
            b2 += gx2[kb + k + 2] * W2[(size_t)(kb + k + 2) * GD + j];
            b3 += gx2[kb + k + 3] * W2[(size_t)(kb + k + 3) * GD + j];
        }
        p2[sub][j] = (a0 + a1) + (b2 + b3);
    }
    __syncthreads();
    if (t < GD)
        ce[t] = fmaxf(0.1f * ((p2[0][t] + p2[1][t]) + (p2[2][t] + p2[3][t]))
                      + 0.9f * init[(size_t)cid * GD + t], 0.f);
    __syncthreads();

    // RNN partials: sub covers k-range [32*sub, 32*sub+32) of feat and ce contributions
    {
        const float* wih = W_ih + (size_t)j * 257;
        const float* whh = W_hh + (size_t)j * GD;
        int kb = sub << 5;
        float a0 = (sub == 0) ? (pc[j] + timediffs[b] * wih[GD]) : 0.f;
        float a1 = 0.f;
#pragma unroll 8
        for (int k = 0; k < 32; k += 2) {
            a0 += feat[kb + k]     * wih[129 + kb + k];
            a1 += feat[kb + k + 1] * wih[129 + kb + k + 1];
        }
#pragma unroll 8
        for (int k = 0; k < 32; k += 2) {
            a0 += ce[kb + k]     * whh[kb + k];
            a1 += ce[kb + k + 1] * whh[kb + k + 1];
        }
        p2[sub][j] = a0 + a1;
    }
    __syncthreads();
    float h = 0.f;
    if (t < GD) {
        h = tanhf((p2[0][t] + p2[1][t]) + (p2[2][t] + p2[3][t]));
        red[t] = h * h;
    }
    __syncthreads();
    for (int s = 64; s > 0; s >>= 1) {
        if (t < s) red[t] += red[t + s];
        __syncthreads();
    }
    if (t < GD) {
        float nrm = fmaxf(sqrtf(red[0]), 1e-12f);
        out[(size_t)b * GD + t] = h / nrm;
    }
}

// ================= launcher (3 launches, no pre-zeroed globals) =================

extern "C" void kernel_launch(void* const* d_in, const int* in_sizes, int n_in,
                              void* d_out, int out_size, void* d_ws, size_t ws_size,
                              hipStream_t stream) {
    const float* code_dynamic = (const float*)d_in[0];
    const float* init_cd      = (const float*)d_in[1];
    const float* patient      = (const float*)d_in[2];
    const float* timediffs    = (const float*)d_in[3];
    const float* features     = (const float*)d_in[4];
    const float* edge_val     = (const float*)d_in[5];
    const float* W1           = (const float*)d_in[6];
    const float* W2           = (const float*)d_in[7];
    const float* W_ih         = (const float*)d_in[8];
    const float* b_ih         = (const float*)d_in[9];
    const float* W_hh         = (const float*)d_in[10];
    const float* b_hh         = (const float*)d_in[11];
    const int* edge_row       = (const int*)d_in[12];
    const int* edge_col       = (const int*)d_in[13];
    const int* codeid         = (const int*)d_in[14];
    const int* patientid      = (const int*)d_in[15];

    int N = in_sizes[0] / GD;   // 60000
    int E = in_sizes[5];        // 600000
    int B = in_sizes[14];       // 256

    // private-segment capacity: max edges one passA block can visit (rounded to 256)
    int MAXH = 256 * ((E + NSEG * 256 - 1) / (NSEG * 256));

    // workspace layout (all 16B-aligned)
    int*   ellc   = (int*)d_ws;                          // N*ELLW
    float* ellv   = (float*)(ellc + (size_t)N * ELLW);   // N*ELLW
    int*   cntarr = (int*)(ellv + (size_t)N * ELLW);     // N (zeroed inside passA)
    int*   list1  = cntarr + N;                          // NSEG*MAXH
    int*   bcnt   = list1 + (size_t)NSEG * MAXH;         // NSEG
    float* pcbuf  = (float*)(bcnt + NSEG);               // GD

    size_t bmBytes = (size_t)((N + 31) / 32) * sizeof(unsigned int);  // 7.5 KB @ N=60000

    passA<<<NSEG, 256, bmBytes, stream>>>(codeid, B, edge_row, edge_col, E,
                                          N, MAXH, list1, bcnt, cntarr,
                                          patient, W_ih, b_ih, b_hh, patientid, pcbuf);
    passB<<<NSEG, 256, bmBytes, stream>>>(edge_row, edge_col, edge_val, E,
                                          codeid, B, list1, bcnt, MAXH, N,
                                          cntarr, ellc, ellv);
    fused12<<<B, 512, 0, stream>>>(code_dynamic, W1, W2, init_cd,
                                   cntarr, ellc, ellv, codeid, timediffs, features,
                                   W_ih, W_hh, pcbuf, (float*)d_out);
}